// Round 9
// baseline (717.123 us; speedup 1.0000x reference)
//
#include <hip/hip_runtime.h>
#include <math.h>

#define NT 4096
#define DP 1024
#define DE 512
#define C0 10000
#define CUT1 30000
#define TAILV 20000
#define WROWS 50112   // 50000 weight rows + zero pad to cover last 128-wide tail tile
#define NBH 79        // head n-blocks (10112/128)
#define NBT 157       // tail n-blocks (ceil(20000/128))

typedef unsigned short ushort_t;
typedef short bf8 __attribute__((ext_vector_type(8)));
typedef float f4 __attribute__((ext_vector_type(4)));

__device__ __forceinline__ ushort_t f2b(float f) {
    union { float f; unsigned int u; } v; v.f = f;
    unsigned int r = v.u + 0x7FFFu + ((v.u >> 16) & 1u);
    return (ushort_t)(r >> 16);
}
__device__ __forceinline__ float b2f(ushort_t u) {
    union { unsigned int u; float f; } v; v.u = ((unsigned int)u) << 16; return v.f;
}

__device__ __forceinline__ void gld16(const void* g, void* l) {
    __builtin_amdgcn_global_load_lds(
        (const __attribute__((address_space(1))) unsigned int*)g,
        (__attribute__((address_space(3))) unsigned int*)l, 16, 0, 0);
}

// bijective XCD-chunk swizzle (m204): each XCD owns a contiguous logical chunk
__device__ __forceinline__ int xcd_swz(int wgid, int nwg) {
    int q = nwg >> 3, r = nwg & 7;
    int xcd = wgid & 7, idx = wgid >> 3;
    int base = (xcd < r) ? xcd * (q + 1) : r * (q + 1) + (xcd - r) * q;
    return base + idx;
}

// ---------------- cluster compaction ----------------
__global__ void cluster_kernel(const int* __restrict__ target,
                               int* __restrict__ cnt, int* __restrict__ list) {
    int t = blockIdx.x * blockDim.x + threadIdx.x;
    if (t >= NT) return;
    int tgt = target[t];
    int c = (tgt < C0) ? 0 : (tgt < CUT1 ? 1 : 2);
    if (c > 0) {
        int pos = atomicAdd(&cnt[c - 1], 1);
        list[(c - 1) * NT + pos] = t;
    }
}

// ---------------- fp32 -> bf16 cast (with zero pad region) ----------------
__global__ __launch_bounds__(256)
void cast_pad(const float* __restrict__ in, ushort_t* __restrict__ out,
              int total4, int valid) {
    int i = blockIdx.x * 256 + threadIdx.x;
    if (i >= total4) return;
    int base = i * 4;
    unsigned long long p = 0ull;
    if (base < valid) {
        float4 v = *reinterpret_cast<const float4*>(in + base);
        p = (unsigned long long)f2b(v.x)
          | ((unsigned long long)f2b(v.y) << 16)
          | ((unsigned long long)f2b(v.z) << 32)
          | ((unsigned long long)f2b(v.w) << 48);
    }
    *reinterpret_cast<unsigned long long*>(out + base) = p;
}

// ---------------- projs [3][1024][512] -> bf16 [3][512][1024] (transpose) ----
__global__ __launch_bounds__(256)
void transpose_cast(const float* __restrict__ projs, ushort_t* __restrict__ out) {
    const int cblk = blockIdx.z;
    const int n0 = blockIdx.x * 32;
    const int k0 = blockIdx.y * 32;
    __shared__ float tile[32][33];
    const int tx = threadIdx.x & 31, ty = threadIdx.x >> 5;
    const float* src = projs + (size_t)cblk * DP * DE;
    #pragma unroll
    for (int j = 0; j < 4; ++j)
        tile[ty + j * 8][tx] = src[(size_t)(k0 + ty + j * 8) * DE + n0 + tx];
    __syncthreads();
    ushort_t* dst = out + (size_t)cblk * DE * DP;
    #pragma unroll
    for (int j = 0; j < 4; ++j)
        dst[(size_t)(n0 + ty + j * 8) * DP + k0 + tx] = f2b(tile[tx][ty + j * 8]);
}

// ---------------- MFMA GEMM: C[m][n] = sum_k A[m][k] * B[n][k] ---------------
// 128x128 tile, BK=64, 4 waves, SINGLE-buffered 32KB LDS (m97/round-5 core:
// compiler-scheduled ds_read/MFMA interleave). 5 blocks/CU; per-block K-loop
// ROTATION (start tile = (logical&3)*NTILES/4) de-phase-locks co-resident
// blocks so their stage drains overlap other blocks' MFMA (m114 coverage).
// MODE 0: proj  (A=hiddenb, B=projsT[z], C bf16 -> Hb[z]); grid x=128, z=3
// MODE 1: FUSED head + 2 tails (exp-sum epilogue -> partials);
//         1D grid 32*(NBH + 2*NBT), segment decoded from logical id.
template<int MODE, int KK>
__global__ __launch_bounds__(256, 5)
void gemm_bt(const ushort_t* __restrict__ A0, const ushort_t* __restrict__ B0,
             ushort_t* __restrict__ Cout, float* __restrict__ Ph,
             float* __restrict__ Pt, const float* __restrict__ bias,
             const int* __restrict__ cnt, const int* __restrict__ list)
{
    constexpr int NTILES = KK >> 6;
    const int tid = threadIdx.x;
    const int lane = tid & 63;
    const int wave = tid >> 6;
    const int wr = wave >> 1, wc = wave & 1;

    const int logical = xcd_swz(blockIdx.x, gridDim.x);
    int mb, nbk, seg = 0, n = 0, validN = 0;
    const ushort_t* Ab;
    const ushort_t* Bb;
    float* Sout = nullptr;
    const float* bvec = nullptr;

    if (MODE == 0) {
        mb = logical & 31; nbk = logical >> 5;
        Ab = A0;
        Bb = B0 + (size_t)blockIdx.z * DE * DP;
        Cout += (size_t)blockIdx.z * (size_t)NT * DE;
    } else {
        int l = logical;
        if (l < 32 * NBH) {
            seg = 0; mb = l & 31; nbk = l >> 5;
            Ab = A0; Bb = B0; bvec = bias; validN = C0; Sout = Ph;
        } else {
            l -= 32 * NBH;
            int z = (l < 32 * NBT) ? 0 : 1;
            if (z) l -= 32 * NBT;
            seg = 1 + z; mb = l & 31; nbk = l >> 5;
            n = cnt[z];
            if (mb * 128 >= n) return;
            Ab = A0 + (size_t)(1 + z) * NT * DE;
            Bb = B0 + (size_t)(C0 + z * TAILV) * DE;
            bvec = bias + C0 + z * TAILV;
            list += z * NT;
            validN = TAILV;
            Sout = Pt + (size_t)z * NBT * NT;
        }
    }
    const int bm = mb * 128, bn = nbk * 128;

    __shared__ __align__(16) unsigned char lds[32768];
    unsigned char* As = lds;
    unsigned char* Bs = lds + 16384;

    // staging: 4 callsites x 4 waves x 64 lanes x 16B covers 128 rows x 128B.
    // LDS is linear [row][128B]; source k-slot is pre-swizzled: slot^=(row&7)
    const int kswz = (lane & 7) ^ ((lane >> 3) & 7);
    const int kbase = kswz * 8;          // element offset of the 16B chunk
    const int srow = wave * 8 + (lane >> 3);

    size_t arow[4], brow[4];
    #pragma unroll
    for (int s = 0; s < 4; ++s) {
        int lr = s * 32 + srow;
        int ga;
        if (MODE == 1 && seg > 0) {
            int gr = bm + lr;
            ga = (gr < n) ? list[gr] : 0;
        } else ga = bm + lr;
        arow[s] = (size_t)ga * KK;
        brow[s] = (size_t)(bn + lr) * KK;
    }

    f4 acc[4][4];
    const f4 zero = {0.f, 0.f, 0.f, 0.f};
    #pragma unroll
    for (int i = 0; i < 4; ++i)
        #pragma unroll
        for (int j = 0; j < 4; ++j) acc[i][j] = zero;

    const int start = (logical & 3) * (NTILES / 4);
    for (int it = 0; it < NTILES; ++it) {
        const int t = (it + start) & (NTILES - 1);
        const int kt = t << 6;
        if (it) __syncthreads();
        #pragma unroll
        for (int s = 0; s < 4; ++s) {
            gld16(A0 + arow[s] + kt + kbase - (A0 - Ab), As + s * 4096 + wave * 1024);
            gld16(Bb + brow[s] + kt + kbase, Bs + s * 4096 + wave * 1024);
        }
        __syncthreads();
        #pragma unroll
        for (int kh = 0; kh < 2; ++kh) {
            bf8 af[4], bv[4];
            #pragma unroll
            for (int i = 0; i < 4; ++i) {
                const int R = wr * 64 + i * 16 + (lane & 15);
                af[i] = *reinterpret_cast<const bf8*>(
                    As + R * 128 + (((kh * 4 + (lane >> 4)) ^ (R & 7)) << 4));
                const int Rb = wc * 64 + i * 16 + (lane & 15);
                bv[i] = *reinterpret_cast<const bf8*>(
                    Bs + Rb * 128 + (((kh * 4 + (lane >> 4)) ^ (Rb & 7)) << 4));
            }
            #pragma unroll
            for (int i = 0; i < 4; ++i)
                #pragma unroll
                for (int j = 0; j < 4; ++j)
                    acc[i][j] = __builtin_amdgcn_mfma_f32_16x16x32_bf16(
                        af[i], bv[j], acc[i][j], 0, 0, 0);
        }
    }

    if (MODE == 0) {
        #pragma unroll
        for (int i = 0; i < 4; ++i) {
            const int row = bm + wr * 64 + i * 16 + ((lane >> 4) << 2);
            #pragma unroll
            for (int j = 0; j < 4; ++j) {
                const int col = bn + wc * 64 + j * 16 + (lane & 15);
                #pragma unroll
                for (int r = 0; r < 4; ++r)
                    Cout[(size_t)(row + r) * DE + col] = f2b(acc[i][j][r]);
            }
        }
    } else {
        float rs[4][4];
        #pragma unroll
        for (int i = 0; i < 4; ++i)
            #pragma unroll
            for (int r = 0; r < 4; ++r) {
                float s = 0.f;
                #pragma unroll
                for (int j = 0; j < 4; ++j) {
                    const int col = bn + wc * 64 + j * 16 + (lane & 15);
                    if (col < validN) s += __expf(acc[i][j][r] + bvec[col]);
                }
                rs[i][r] = s;
            }
        #pragma unroll
        for (int m = 1; m < 16; m <<= 1)
            #pragma unroll
            for (int i = 0; i < 4; ++i)
                #pragma unroll
                for (int r = 0; r < 4; ++r)
                    rs[i][r] += __shfl_xor(rs[i][r], m);
        // cross-wave combine in LDS (reuse staging buffer), then plain store
        float* ps = (float*)lds;     // ps[wc][row], 2 x 128 floats
        __syncthreads();             // everyone done reading As/Bs
        if ((lane & 15) == 0) {
            const int rb = (lane >> 4) << 2;
            #pragma unroll
            for (int i = 0; i < 4; ++i)
                #pragma unroll
                for (int r = 0; r < 4; ++r)
                    ps[wc * 128 + wr * 64 + i * 16 + rb + r] = rs[i][r];
        }
        __syncthreads();
        if (tid < 128) {
            float v = ps[tid] + ps[128 + tid];
            Sout[(size_t)nbk * NT + bm + tid] = v;   // partial; garbage rows unread
        }
    }
}

// ---------------- partial reduce: S = sum over n-blocks (no atomics) ---------
__global__ __launch_bounds__(256)
void reduce_kernel(const float* __restrict__ Ph, const float* __restrict__ Pt,
                   const int* __restrict__ cnt, const int* __restrict__ list,
                   float* __restrict__ S_head, float* __restrict__ S_tail) {
    const int z = blockIdx.y;
    const int t = blockIdx.x * 256 + threadIdx.x;
    if (z == 0) {
        if (t >= NT) return;
        float s = 0.f;
        for (int nb = 0; nb < NBH; ++nb) s += Ph[(size_t)nb * NT + t];
        S_head[t] = s;
    } else {
        const int tail = z - 1;
        if (t >= cnt[tail]) return;
        const float* P = Pt + (size_t)tail * NBT * NT;
        float s = 0.f;
        for (int nb = 0; nb < NBT; ++nb) s += P[(size_t)nb * NT + t];
        S_tail[list[tail * NT + t]] = s;
    }
}

// ---------------- finalize: cluster logits + target logit + NLL --------------
__global__ __launch_bounds__(64)
void finalize_kernel(const ushort_t* __restrict__ Hb, const int* __restrict__ target,
                     const float* __restrict__ weight, const float* __restrict__ bias,
                     const float* __restrict__ cw, const float* __restrict__ cb,
                     const float* __restrict__ S_head, const float* __restrict__ S_tail,
                     float* __restrict__ out)
{
    const int t = blockIdx.x, lane = threadIdx.x;
    const int tgt = target[t];
    const int c = (tgt < C0) ? 0 : (tgt < CUT1 ? 1 : 2);
    const int e = lane * 8;

    union { uint4 u; ushort_t s[8]; } h0;
    h0.u = *reinterpret_cast<const uint4*>(Hb + (size_t)t * DE + e);
    float hv[8];
    #pragma unroll
    for (int k = 0; k < 8; ++k) hv[k] = b2f(h0.s[k]);

    float c1 = 0.f, c2 = 0.f;
    #pragma unroll
    for (int k = 0; k < 8; ++k) {
        c1 += hv[k] * cw[e + k];
        c2 += hv[k] * cw[DE + e + k];
    }

    const ushort_t* hs = (c == 0) ? (Hb + (size_t)t * DE)
                                  : (Hb + ((size_t)c * NT + (size_t)t) * DE);
    union { uint4 u; ushort_t s[8]; } hc;
    hc.u = *reinterpret_cast<const uint4*>(hs + e);
    const float* wt = weight + (size_t)tgt * DE;
    float dt = 0.f;
    #pragma unroll
    for (int k = 0; k < 8; ++k) dt += b2f(hc.s[k]) * wt[e + k];

    #pragma unroll
    for (int m = 32; m; m >>= 1) {
        c1 += __shfl_xor(c1, m);
        c2 += __shfl_xor(c2, m);
        dt += __shfl_xor(dt, m);
    }
    if (lane == 0) {
        c1 += cb[0]; c2 += cb[1];
        const float S = S_head[t] + __expf(c1) + __expf(c2);
        const float lsh = logf(S);
        float res;
        if (c == 0) {
            res = lsh - (dt + bias[tgt]);
        } else {
            const float cl = (c == 1) ? c1 : c2;
            res = (lsh - cl) + (logf(S_tail[t]) - (dt + bias[tgt]));
        }
        out[t] = res;
    }
}

extern "C" void kernel_launch(void* const* d_in, const int* in_sizes, int n_in,
                              void* d_out, int out_size, void* d_ws, size_t ws_size,
                              hipStream_t stream) {
    const float* hidden = (const float*)d_in[0];
    const int*   target = (const int*)d_in[1];
    const float* weight = (const float*)d_in[2];
    const float* bias   = (const float*)d_in[3];
    const float* cw     = (const float*)d_in[4];
    const float* cb     = (const float*)d_in[5];
    const float* projs  = (const float*)d_in[6];
    float* out = (float*)d_out;

    char* w = (char*)d_ws;
    ushort_t* Hb      = (ushort_t*)w;  w += (size_t)3 * NT * DE * 2;
    ushort_t* hiddenb = (ushort_t*)w;  w += (size_t)NT * DP * 2;
    ushort_t* Wb      = (ushort_t*)w;  w += (size_t)WROWS * DE * 2;
    ushort_t* projsTb = (ushort_t*)w;  w += (size_t)3 * DE * DP * 2;
    float* S_head = (float*)w;         w += NT * 4;
    float* S_tail = (float*)w;         w += NT * 4;
    int* cnt      = (int*)w;           w += 32;
    int* list     = (int*)w;           w += 2 * NT * 4;
    float* Ph     = (float*)w;         w += (size_t)NBH * NT * 4;
    float* Pt     = (float*)w;         w += (size_t)2 * NBT * NT * 4;

    hipMemsetAsync(cnt, 0, 32, stream);
    cluster_kernel<<<NT / 256, 256, 0, stream>>>(target, cnt, list);
    cast_pad<<<(NT * DP / 4 + 255) / 256, 256, 0, stream>>>(
        hidden, hiddenb, NT * DP / 4, NT * DP);
    cast_pad<<<(WROWS * DE / 4 + 255) / 256, 256, 0, stream>>>(
        weight, Wb, WROWS * DE / 4, 50000 * DE);
    transpose_cast<<<dim3(DE / 32, DP / 32, 3), 256, 0, stream>>>(projs, projsTb);

    // proj: 32 mb x 4 nb (m-fastest), 3 clusters
    gemm_bt<0, DP><<<dim3(32 * 4, 1, 3), 256, 0, stream>>>(
        hiddenb, projsTb, Hb, nullptr, nullptr, nullptr, nullptr, nullptr);
    // FUSED head + 2 tails, one 1D dispatch (m-fastest within segments)
    gemm_bt<1, DE><<<dim3(32 * (NBH + 2 * NBT), 1, 1), 256, 0, stream>>>(
        Hb, Wb, nullptr, Ph, Pt, bias, cnt, list);

    reduce_kernel<<<dim3(NT / 256, 3), 256, 0, stream>>>(
        Ph, Pt, cnt, list, S_head, S_tail);
    finalize_kernel<<<NT, 64, 0, stream>>>(
        Hb, target, weight, bias, cw, cb, S_head, S_tail, out);
}